// Round 6
// baseline (1508.931 us; speedup 1.0000x reference)
//
#include <hip/hip_runtime.h>

#define BATCH 32
#define PIX   3072
#define NEU   4096
#define STEPS 99           // reference runs NUM_STEPS-1 = 99 update iterations
#define ETA   (0.001f / 0.03f)
#define NBLK  256          // 2 independent half-batch systems x 128 col-groups
#define TPB   512
#define SLOT  (BATCH * NEU)          // halves per rotating a-buffer (256 KB)

typedef __bf16 bf16x8 __attribute__((ext_vector_type(8)));
typedef float  f32x4  __attribute__((ext_vector_type(4)));
typedef unsigned long long u64;

__device__ __forceinline__ float softt(float u, float lam) {
    return u > lam ? u - lam : (u < -lam ? u + lam : 0.0f);
}

// fp32 -> bf16 round-to-nearest-even.  Cannot produce 0xFFFF (NaN pattern)
// from finite input => 0xFFFF is a safe sentinel.
__device__ __forceinline__ unsigned short f2b(float f) {
    unsigned int u = __builtin_bit_cast(unsigned int, f);
    u = (u + 0x7FFFu + ((u >> 16) & 1u)) >> 16;
    return (unsigned short)u;
}

__device__ __forceinline__ bf16x8 ldfrag_g(const unsigned short* p) {
    uint4 v = *(const uint4*)p;
    return __builtin_bit_cast(bf16x8, v);
}

// ---------------------------------------------------------------------------
// φ (fp32 [PIX][NEU]) -> φT (bf16 [NEU][PIX]).  64x64 tiles via LDS.
__global__ void transp(const float* __restrict__ phi, unsigned short* __restrict__ phiT) {
    __shared__ float t[64][65];
    const int n0 = blockIdx.x * 64, p0 = blockIdx.y * 64;
    const int tid = threadIdx.x;
    #pragma unroll
    for (int pass = 0; pass < 4; ++pass) {
        const int r  = pass * 16 + (tid >> 4);
        const int c4 = (tid & 15) * 4;
        float4 v = *(const float4*)(phi + (size_t)(p0 + r) * NEU + n0 + c4);
        t[r][c4 + 0] = v.x; t[r][c4 + 1] = v.y; t[r][c4 + 2] = v.z; t[r][c4 + 3] = v.w;
    }
    __syncthreads();
    #pragma unroll
    for (int pass = 0; pass < 2; ++pass) {
        const int cp = pass * 32 + (tid >> 3);
        const int p8 = (tid & 7) * 8;
        unsigned int w0 = (unsigned int)f2b(t[p8 + 0][cp]) | ((unsigned int)f2b(t[p8 + 1][cp]) << 16);
        unsigned int w1 = (unsigned int)f2b(t[p8 + 2][cp]) | ((unsigned int)f2b(t[p8 + 3][cp]) << 16);
        unsigned int w2 = (unsigned int)f2b(t[p8 + 4][cp]) | ((unsigned int)f2b(t[p8 + 5][cp]) << 16);
        unsigned int w3 = (unsigned int)f2b(t[p8 + 6][cp]) | ((unsigned int)f2b(t[p8 + 7][cp]) << 16);
        uint4 o = make_uint4(w0, w1, w2, w3);
        *(uint4*)(phiT + (size_t)(n0 + cp) * PIX + p0 + p8) = o;
    }
}

// ---------------------------------------------------------------------------
// G = φᵀφ (symmetric, bf16). Upper-triangle blocks only; mirror-store.
__global__ void gemm_G(const unsigned short* __restrict__ phiT, unsigned short* __restrict__ G) {
    if (blockIdx.y > blockIdx.x) return;
    __shared__ __align__(16) unsigned short lds[2][128 * 40];
    const int m0 = blockIdx.y * 128, n0 = blockIdx.x * 128;
    const int tid  = threadIdx.x;
    const int lane = tid & 63, w = tid >> 6;
    const int wm = (w & 1) * 64, wn = (w >> 1) * 64;
    const int q8 = (lane >> 4) * 8, l15 = lane & 15;
    f32x4 acc[4][4] = {};
    for (int k0 = 0; k0 < PIX; k0 += 32) {
        __syncthreads();
        #pragma unroll
        for (int it = 0; it < 2; ++it) {
            const int id = tid + 256 * it;
            const int row = id >> 2, q = id & 3;
            uint4 va = *(const uint4*)(phiT + (size_t)(m0 + row) * PIX + k0 + q * 8);
            *(uint4*)(&lds[0][row * 40 + q * 8]) = va;
            uint4 vb = *(const uint4*)(phiT + (size_t)(n0 + row) * PIX + k0 + q * 8);
            *(uint4*)(&lds[1][row * 40 + q * 8]) = vb;
        }
        __syncthreads();
        bf16x8 af[4], bfr[4];
        #pragma unroll
        for (int i = 0; i < 4; ++i) {
            af[i]  = *(const bf16x8*)(&lds[0][(wm + i * 16 + l15) * 40 + q8]);
            bfr[i] = *(const bf16x8*)(&lds[1][(wn + i * 16 + l15) * 40 + q8]);
        }
        #pragma unroll
        for (int i = 0; i < 4; ++i)
            #pragma unroll
            for (int j = 0; j < 4; ++j)
                acc[i][j] = __builtin_amdgcn_mfma_f32_16x16x32_bf16(af[i], bfr[j], acc[i][j], 0, 0, 0);
    }
    const int q = lane >> 4;
    const bool offdiag = (blockIdx.y != blockIdx.x);
    #pragma unroll
    for (int i = 0; i < 4; ++i)
        #pragma unroll
        for (int j = 0; j < 4; ++j) {
            unsigned short pk[4];
            #pragma unroll
            for (int r = 0; r < 4; ++r) {
                const int gm = m0 + wm + i * 16 + q * 4 + r;
                const int gn = n0 + wn + j * 16 + l15;
                const unsigned short v = f2b(acc[i][j][r]);
                G[(size_t)gm * NEU + gn] = v;
                pk[r] = v;
            }
            if (offdiag) {
                const int gm0 = m0 + wm + i * 16 + q * 4;
                const int gn  = n0 + wn + j * 16 + l15;
                *(ushort4*)(G + (size_t)gn * NEU + gm0) = make_ushort4(pk[0], pk[1], pk[2], pk[3]);
            }
        }
}

// ---------------------------------------------------------------------------
// b = x @ phi.  grid 256 (16-col strips), block 512
__global__ void lca_binit(const float* __restrict__ x, const unsigned short* __restrict__ phiT,
                          float* __restrict__ b) {
    __shared__ float red[8 * 512];
    const int tid = threadIdx.x;
    const int lane = tid & 63, w = tid >> 6;
    const int n0 = blockIdx.x * 16;
    const int kbase = w * (PIX / 8);
    const int q8 = (lane >> 4) * 8, l15 = lane & 15;
    f32x4 acc[2] = {};
    const unsigned short* Brow = phiT + (size_t)(n0 + l15) * PIX + kbase + q8;
    const float* X0 = x + (size_t)l15 * PIX + kbase + q8;
    const float* X1 = x + (size_t)(16 + l15) * PIX + kbase + q8;
    #pragma unroll 4
    for (int kk = 0; kk < PIX / 8; kk += 32) {
        bf16x8 bg = ldfrag_g(Brow + kk);
        float4 xa0 = *(const float4*)(X0 + kk), xb0 = *(const float4*)(X0 + kk + 4);
        float4 xa1 = *(const float4*)(X1 + kk), xb1 = *(const float4*)(X1 + kk + 4);
        bf16x8 a0, a1;
        a0[0]=(__bf16)xa0.x; a0[1]=(__bf16)xa0.y; a0[2]=(__bf16)xa0.z; a0[3]=(__bf16)xa0.w;
        a0[4]=(__bf16)xb0.x; a0[5]=(__bf16)xb0.y; a0[6]=(__bf16)xb0.z; a0[7]=(__bf16)xb0.w;
        a1[0]=(__bf16)xa1.x; a1[1]=(__bf16)xa1.y; a1[2]=(__bf16)xa1.z; a1[3]=(__bf16)xa1.w;
        a1[4]=(__bf16)xb1.x; a1[5]=(__bf16)xb1.y; a1[6]=(__bf16)xb1.z; a1[7]=(__bf16)xb1.w;
        acc[0] = __builtin_amdgcn_mfma_f32_16x16x32_bf16(a0, bg, acc[0], 0, 0, 0);
        acc[1] = __builtin_amdgcn_mfma_f32_16x16x32_bf16(a1, bg, acc[1], 0, 0, 0);
    }
    const int q = lane >> 4;
    #pragma unroll
    for (int mt = 0; mt < 2; ++mt)
        #pragma unroll
        for (int r = 0; r < 4; ++r)
            red[w * 512 + (mt * 16 + q * 4 + r) * 16 + l15] = acc[mt][r];
    __syncthreads();
    float s = 0.f;
    #pragma unroll
    for (int w8 = 0; w8 < 8; ++w8) s += red[w8 * 512 + tid];
    const int m = tid >> 4, n = n0 + (tid & 15);
    b[(size_t)m * NEU + n] = s;
}

// ---------------------------------------------------------------------------
// Pre-fill the rotating exchange region with the sentinel (bf16 0xFFFF).
// Agent write-through stores so the sentinel is at the coherence point, where
// the consumers' agent loads will read.
__global__ void fillsent(u64* __restrict__ rot, size_t n64) {
    size_t i = (size_t)blockIdx.x * blockDim.x + threadIdx.x;
    const size_t stride = (size_t)gridDim.x * blockDim.x;
    for (; i < n64; i += stride)
        __hip_atomic_store(rot + i, ~0ULL, __ATOMIC_RELAXED, __HIP_MEMORY_SCOPE_AGENT);
}

// ---------------------------------------------------------------------------
// publish this thread's single a-value: gather 4 consecutive lanes' bf16
// pairs into one 8-B agent-scope write-through store.  The 8-B packet is a
// single store instruction => single-copy atomic: a consumer sees either the
// full sentinel or full data in each half (dword), never a torn mix.
__device__ __forceinline__ void publish16(unsigned short* slot, size_t idx,
                                          float av, int lane) {
    unsigned int v  = f2b(av);
    unsigned int d0 = v | ((unsigned int)__shfl_xor((int)v, 1, 64) << 16);
    unsigned int hi = (unsigned int)__shfl_xor((int)d0, 2, 64);
    if ((lane & 3) == 0) {
        u64 val = (u64)d0 | ((u64)hi << 32);
        __hip_atomic_store((u64*)slot + (idx >> 2), val,
                           __ATOMIC_RELAXED, __HIP_MEMORY_SCOPE_AGENT);
    }
}

// --- sentinel-validated A-batch: 8 fragments = 16 x 8-B agent loads --------
__device__ __forceinline__ void agent_ld16(const u64* base, u64 v[16]) {
    #pragma unroll
    for (int f = 0; f < 8; ++f) {
        v[2 * f]     = __hip_atomic_load(base + f * 8,     __ATOMIC_RELAXED,
                                         __HIP_MEMORY_SCOPE_AGENT);
        v[2 * f + 1] = __hip_atomic_load(base + f * 8 + 1, __ATOMIC_RELAXED,
                                         __HIP_MEMORY_SCOPE_AGENT);
    }
}
__device__ __forceinline__ unsigned chk16(const u64 v[16]) {
    unsigned bad = 0;
    #pragma unroll
    for (int i = 0; i < 16; ++i)
        bad |= (unsigned)(((unsigned)v[i] == ~0u) | ((unsigned)(v[i] >> 32) == ~0u));
    return bad;
}
__device__ __forceinline__ void validate16(const u64* base, u64 v[16]) {
    unsigned bad = chk16(v);
    while (__ballot(bad)) {
        agent_ld16(base, v);
        bad = chk16(v);
    }
}
__device__ __forceinline__ bf16x8 frag_of(u64 lo, u64 hi) {
    uint4 t = make_uint4((unsigned)lo, (unsigned)(lo >> 32),
                         (unsigned)hi, (unsigned)(hi >> 32));
    return __builtin_bit_cast(bf16x8, t);
}

// ---------------------------------------------------------------------------
// Persistent kernel, 256 blocks x 512 thr -- ALL 256 CUs active.
// Two independent 16-row half-systems x 128 col-groups (32 cols each).
//
// PURE SENTINEL EXCHANGE (no flags, no grid sync):
//   - rot pre-filled with 0xFFFF sentinel (fillsent, agent write-through).
//   - producers publish 8-B agent packets and proceed immediately: no drain,
//     no flag, no barrier on the publish path.
//   - consumers read A ONLY via agent-scope 8-B atomic loads (bypass L1/L2,
//     served at the coherence point -- same primitive as the proven flag
//     poll), validate per-dword against the sentinel, and re-issue only
//     not-yet-arrived batches.  The load retry IS the synchronization.
//   - slots are write-once (98-deep rotation) => no ABA; publish precedes
//     every wait => forward-only dependency DAG => no deadlock.
//   - red[] is double-buffered by step parity => ONE __syncthreads per step
//     (at which vmcnt is naturally ~0: A-loads consumed, publish long acked).
__global__ void __launch_bounds__(TPB, 2)
lca_persist(const unsigned short* __restrict__ G, const float* __restrict__ b,
            unsigned short* __restrict__ rot, float* __restrict__ aout,
            const float* __restrict__ lamp) {
    __shared__ float red[2][8 * 512];
    const int tid  = threadIdx.x;
    const int lane = tid & 63, w = tid >> 6;        // 8 waves
    const int l15  = lane & 15, q = lane >> 4;
    const int q8   = q * 8;
    const int c    = blockIdx.x & 127;              // column group (32 cols)
    const int h    = blockIdx.x >> 7;               // batch half (16 rows)
    const int n0   = c * 32;
    const int rb   = h * 16;                        // first batch row
    const int kbase = w * (NEU / 8);                // 512 k per wave

    // --- G fragments: 2 n-tiles x 16 k-frags, loaded once, loop-invariant.
    bf16x8 gf[2][16];
    #pragma unroll
    for (int j = 0; j < 2; ++j)
        #pragma unroll
        for (int f = 0; f < 16; ++f)
            gf[j][f] = ldfrag_g(G + (size_t)(n0 + j * 16 + l15) * NEU + kbase + f * 32 + q8);

    // --- per-thread state: ONE output (row = rb + tid>>5, col = n0 + tid&31)
    const int m0i = tid >> 5, nn0 = tid & 31;
    const size_t idx0 = (size_t)(rb + m0i) * NEU + n0 + nn0;
    const float bv0 = b[idx0];
    const float lam = lamp[0];

    // --- step 0 entirely in-register: u1 = ETA*b, a1 = soft(u1) ---
    float uv0 = ETA * bv0;
    float av0 = softt(uv0, lam);

    // lane's A-read base (u64 units): row rb+l15, k-range [kbase, kbase+512)
    const size_t aoff0 = (size_t)(rb + l15) * NEU + kbase + q8;   // halves
    const size_t au64  = aoff0 >> 2;                              // u64 index

    publish16(rot, idx0, av0, lane);                 // rot[0]

    for (int step = 1; step < STEPS; ++step) {       // steps 1..98
        const u64* A64 = (const u64*)(rot + (size_t)(step - 1) * SLOT) + au64;
        const int  p   = step & 1;

        // batch 1: fragments 0..7 (k = kbase .. kbase+256)
        u64 v0[16];
        agent_ld16(A64, v0);

        f32x4 acc00 = {}, acc01 = {};
        validate16(A64, v0);
        #pragma unroll
        for (int f = 0; f < 8; ++f) {
            bf16x8 s = frag_of(v0[2 * f], v0[2 * f + 1]);
            acc00 = __builtin_amdgcn_mfma_f32_16x16x32_bf16(s, gf[0][f], acc00, 0, 0, 0);
            acc01 = __builtin_amdgcn_mfma_f32_16x16x32_bf16(s, gf[1][f], acc01, 0, 0, 0);
        }
        // batch 2: fragments 8..15
        u64 v1[16];
        agent_ld16(A64 + 64, v1);
        validate16(A64 + 64, v1);
        #pragma unroll
        for (int f = 0; f < 8; ++f) {
            bf16x8 s = frag_of(v1[2 * f], v1[2 * f + 1]);
            acc00 = __builtin_amdgcn_mfma_f32_16x16x32_bf16(s, gf[0][8 + f], acc00, 0, 0, 0);
            acc01 = __builtin_amdgcn_mfma_f32_16x16x32_bf16(s, gf[1][8 + f], acc01, 0, 0, 0);
        }

        // stage partials into parity buffer: red[p][w][ m*32 + nn ]
        #pragma unroll
        for (int r = 0; r < 4; ++r) {
            red[p][w * 512 + (q * 4 + r) * 32 + l15]      = acc00[r];
            red[p][w * 512 + (q * 4 + r) * 32 + 16 + l15] = acc01[r];
        }
        __syncthreads();   // partials visible; prior-parity buffer free
        float s0v = 0.f;
        #pragma unroll
        for (int w8 = 0; w8 < 8; ++w8) s0v += red[p][w8 * 512 + tid];

        uv0 = fmaf(ETA, bv0 - s0v + av0 - uv0, uv0);
        av0 = softt(uv0, lam);

        if (step == STEPS - 1) {
            aout[idx0] = av0;
        } else {
            publish16(rot + (size_t)step * SLOT, idx0, av0, lane);
        }
    }
}

// ===========================================================================
// Fallback fp32 path (round-1, known correct) for small ws_size
// ===========================================================================
__global__ void lca_init_f(const float* __restrict__ x, const float* __restrict__ phi,
                           float* __restrict__ b, float* __restrict__ u,
                           float* __restrict__ a) {
    const int n  = blockIdx.x * 64 + (threadIdx.x & 63);
    const int bi = blockIdx.y * 4 + (threadIdx.x >> 6);
    const float* xr = x + bi * PIX;
    float acc = 0.f;
    #pragma unroll 4
    for (int p = 0; p < PIX; ++p) acc = fmaf(xr[p], phi[p * NEU + n], acc);
    const int idx = bi * NEU + n;
    b[idx] = acc; u[idx] = 0.f; a[idx] = 0.f;
}
__global__ void lca_s_f(const float* __restrict__ a, const float* __restrict__ phi,
                        float* __restrict__ s) {
    const int lane = threadIdx.x & 63, w = threadIdx.x >> 6;
    const int bi = blockIdx.y, p0 = (blockIdx.x * 4 + w) * 8;
    const float* ar = a + bi * NEU;
    float acc[8] = {};
    for (int i = 0; i < NEU / 64; ++i) {
        const int n = i * 64 + lane;
        const float av = ar[n];
        #pragma unroll
        for (int j = 0; j < 8; ++j) acc[j] = fmaf(av, phi[(p0 + j) * NEU + n], acc[j]);
    }
    float out = 0.f;
    #pragma unroll
    for (int j = 0; j < 8; ++j) {
        float v = acc[j];
        v += __shfl_xor(v, 1, 64); v += __shfl_xor(v, 2, 64); v += __shfl_xor(v, 4, 64);
        v += __shfl_xor(v, 8, 64); v += __shfl_xor(v, 16, 64); v += __shfl_xor(v, 32, 64);
        if (lane == j) out = v;
    }
    if (lane < 8) s[bi * PIX + p0 + lane] = out;
}
__global__ void lca_t_f(const float* __restrict__ s, const float* __restrict__ phi,
                        const float* __restrict__ b, float* __restrict__ u,
                        float* __restrict__ a, const float* __restrict__ lamp) {
    __shared__ float ls[8 * 256];
    const int n = blockIdx.x * 64 + (threadIdx.x & 63);
    const int slot = threadIdx.x >> 6;
    const int bb = blockIdx.y * 8 + slot;
    float acc = 0.f;
    for (int c = 0; c < PIX; c += 256) {
        __syncthreads();
        for (int e = threadIdx.x; e < 8 * 256; e += 512) {
            const int r = e >> 8, p = e & 255;
            ls[e] = s[(blockIdx.y * 8 + r) * PIX + c + p];
        }
        __syncthreads();
        const float* lrow = ls + slot * 256;
        #pragma unroll 8
        for (int p = 0; p < 256; ++p) acc = fmaf(lrow[p], phi[(c + p) * NEU + n], acc);
    }
    const float lam = lamp[0];
    const int idx = bb * NEU + n;
    const float uo = u[idx];
    const float du = b[idx] - acc + a[idx] - uo;
    const float un = fmaf(ETA, du, uo);
    u[idx] = un; a[idx] = softt(un, lam);
}

// ===========================================================================
extern "C" void kernel_launch(void* const* d_in, const int* in_sizes, int n_in,
                              void* d_out, int out_size, void* d_ws, size_t ws_size,
                              hipStream_t stream) {
    const float* x    = (const float*)d_in[0];
    const float* phi  = (const float*)d_in[1];
    const float* lamp = (const float*)d_in[2];
    float* a = (float*)d_out;
    char* ws = (char*)d_ws;

    // rot region (98 x 256 KB) overlays phiT (24 MB): phiT is dead once
    // lca_binit completes; fillsent (sentinel pre-fill) runs AFTER binit
    // and before lca_persist (stream order => visibility).
    const size_t ROT_OFF  = 0;
    const size_t ROT_BYTES= (size_t)(STEPS - 1) * SLOT * 2;         // 25.69 MB
    const size_t PHIT_OFF = 0;                                       // overlay
    const size_t G_OFF    = ROT_OFF + ROT_BYTES;                     // 25.69 MB
    const size_t B_OFF    = G_OFF + (size_t)NEU * NEU * 2;           // +32 MB
    const size_t NEED     = B_OFF + (size_t)BATCH * NEU * 4;         // ~58 MB

    if (ws_size >= NEED) {
        unsigned short* phiT = (unsigned short*)(ws + PHIT_OFF);
        unsigned short* rot  = (unsigned short*)(ws + ROT_OFF);
        unsigned short* G    = (unsigned short*)(ws + G_OFF);
        float*          b    = (float*)(ws + B_OFF);

        transp<<<dim3(NEU / 64, PIX / 64), 256, 0, stream>>>(phi, phiT);
        gemm_G<<<dim3(32, 32), 256, 0, stream>>>(phiT, G);
        lca_binit<<<256, 512, 0, stream>>>(x, phiT, b);
        fillsent<<<1024, 512, 0, stream>>>((u64*)rot, ROT_BYTES / 8);

        void* args[5];
        const unsigned short* Gc = G;
        const float* bc = b;
        const float* lc = lamp;
        args[0] = (void*)&Gc;
        args[1] = (void*)&bc;
        args[2] = (void*)&rot;
        args[3] = (void*)&a;
        args[4] = (void*)&lc;
        hipLaunchCooperativeKernel((const void*)lca_persist, dim3(NBLK), dim3(TPB),
                                   args, 0, stream);
    } else {
        float* fws = (float*)d_ws;
        float* b = fws;
        float* u = fws + BATCH * NEU;
        float* s = fws + 2 * BATCH * NEU;
        lca_init_f<<<dim3(64, 8), 256, 0, stream>>>(x, phi, b, u, a);
        for (int it = 0; it < STEPS; ++it) {
            lca_s_f<<<dim3(96, 32), 256, 0, stream>>>(a, phi, s);
            lca_t_f<<<dim3(64, 4), 512, 0, stream>>>(s, phi, b, u, a, lamp);
        }
    }
}

// Round 7
// 784.140 us; speedup vs baseline: 1.9243x; 1.9243x over previous
//
#include <hip/hip_runtime.h>

#define BATCH 32
#define PIX   3072
#define NEU   4096
#define STEPS 99           // reference runs NUM_STEPS-1 = 99 update iterations
#define ETA   (0.001f / 0.03f)
#define NBLK  256          // 2 independent half-batch systems x 128 col-groups
#define TPB   512
#define SLOT  (BATCH * NEU)          // halves per rotating a-buffer (256 KB)

typedef __bf16 bf16x8 __attribute__((ext_vector_type(8)));
typedef float  f32x4  __attribute__((ext_vector_type(4)));

__device__ __forceinline__ float softt(float u, float lam) {
    return u > lam ? u - lam : (u < -lam ? u + lam : 0.0f);
}

// fp32 -> bf16 round-to-nearest-even
__device__ __forceinline__ unsigned short f2b(float f) {
    unsigned int u = __builtin_bit_cast(unsigned int, f);
    u = (u + 0x7FFFu + ((u >> 16) & 1u)) >> 16;
    return (unsigned short)u;
}

__device__ __forceinline__ bf16x8 ldfrag_g(const unsigned short* p) {
    uint4 v = *(const uint4*)p;
    return __builtin_bit_cast(bf16x8, v);
}

// ---------------------------------------------------------------------------
// φ (fp32 [PIX][NEU]) -> φT (bf16 [NEU][PIX]).  64x64 tiles via LDS.
__global__ void transp(const float* __restrict__ phi, unsigned short* __restrict__ phiT) {
    __shared__ float t[64][65];
    const int n0 = blockIdx.x * 64, p0 = blockIdx.y * 64;
    const int tid = threadIdx.x;
    #pragma unroll
    for (int pass = 0; pass < 4; ++pass) {
        const int r  = pass * 16 + (tid >> 4);
        const int c4 = (tid & 15) * 4;
        float4 v = *(const float4*)(phi + (size_t)(p0 + r) * NEU + n0 + c4);
        t[r][c4 + 0] = v.x; t[r][c4 + 1] = v.y; t[r][c4 + 2] = v.z; t[r][c4 + 3] = v.w;
    }
    __syncthreads();
    #pragma unroll
    for (int pass = 0; pass < 2; ++pass) {
        const int cp = pass * 32 + (tid >> 3);
        const int p8 = (tid & 7) * 8;
        unsigned int w0 = (unsigned int)f2b(t[p8 + 0][cp]) | ((unsigned int)f2b(t[p8 + 1][cp]) << 16);
        unsigned int w1 = (unsigned int)f2b(t[p8 + 2][cp]) | ((unsigned int)f2b(t[p8 + 3][cp]) << 16);
        unsigned int w2 = (unsigned int)f2b(t[p8 + 4][cp]) | ((unsigned int)f2b(t[p8 + 5][cp]) << 16);
        unsigned int w3 = (unsigned int)f2b(t[p8 + 6][cp]) | ((unsigned int)f2b(t[p8 + 7][cp]) << 16);
        uint4 o = make_uint4(w0, w1, w2, w3);
        *(uint4*)(phiT + (size_t)(n0 + cp) * PIX + p0 + p8) = o;
    }
}

// ---------------------------------------------------------------------------
// G = φᵀφ (symmetric, bf16). Upper-triangle blocks only; mirror-store.
__global__ void gemm_G(const unsigned short* __restrict__ phiT, unsigned short* __restrict__ G) {
    if (blockIdx.y > blockIdx.x) return;
    __shared__ __align__(16) unsigned short lds[2][128 * 40];
    const int m0 = blockIdx.y * 128, n0 = blockIdx.x * 128;
    const int tid  = threadIdx.x;
    const int lane = tid & 63, w = tid >> 6;
    const int wm = (w & 1) * 64, wn = (w >> 1) * 64;
    const int q8 = (lane >> 4) * 8, l15 = lane & 15;
    f32x4 acc[4][4] = {};
    for (int k0 = 0; k0 < PIX; k0 += 32) {
        __syncthreads();
        #pragma unroll
        for (int it = 0; it < 2; ++it) {
            const int id = tid + 256 * it;
            const int row = id >> 2, q = id & 3;
            uint4 va = *(const uint4*)(phiT + (size_t)(m0 + row) * PIX + k0 + q * 8);
            *(uint4*)(&lds[0][row * 40 + q * 8]) = va;
            uint4 vb = *(const uint4*)(phiT + (size_t)(n0 + row) * PIX + k0 + q * 8);
            *(uint4*)(&lds[1][row * 40 + q * 8]) = vb;
        }
        __syncthreads();
        bf16x8 af[4], bfr[4];
        #pragma unroll
        for (int i = 0; i < 4; ++i) {
            af[i]  = *(const bf16x8*)(&lds[0][(wm + i * 16 + l15) * 40 + q8]);
            bfr[i] = *(const bf16x8*)(&lds[1][(wn + i * 16 + l15) * 40 + q8]);
        }
        #pragma unroll
        for (int i = 0; i < 4; ++i)
            #pragma unroll
            for (int j = 0; j < 4; ++j)
                acc[i][j] = __builtin_amdgcn_mfma_f32_16x16x32_bf16(af[i], bfr[j], acc[i][j], 0, 0, 0);
    }
    const int q = lane >> 4;
    const bool offdiag = (blockIdx.y != blockIdx.x);
    #pragma unroll
    for (int i = 0; i < 4; ++i)
        #pragma unroll
        for (int j = 0; j < 4; ++j) {
            unsigned short pk[4];
            #pragma unroll
            for (int r = 0; r < 4; ++r) {
                const int gm = m0 + wm + i * 16 + q * 4 + r;
                const int gn = n0 + wn + j * 16 + l15;
                const unsigned short v = f2b(acc[i][j][r]);
                G[(size_t)gm * NEU + gn] = v;
                pk[r] = v;
            }
            if (offdiag) {
                const int gm0 = m0 + wm + i * 16 + q * 4;
                const int gn  = n0 + wn + j * 16 + l15;
                *(ushort4*)(G + (size_t)gn * NEU + gm0) = make_ushort4(pk[0], pk[1], pk[2], pk[3]);
            }
        }
}

// ---------------------------------------------------------------------------
// b = x @ phi; zero the 256 producer flags (64-B padded).
// grid 256 (16-col strips), block 512
__global__ void lca_binit(const float* __restrict__ x, const unsigned short* __restrict__ phiT,
                          float* __restrict__ b, unsigned int* __restrict__ arr) {
    __shared__ float red[8 * 512];
    const int tid = threadIdx.x;
    const int lane = tid & 63, w = tid >> 6;
    const int n0 = blockIdx.x * 16;
    const int kbase = w * (PIX / 8);
    const int q8 = (lane >> 4) * 8, l15 = lane & 15;
    if (blockIdx.x < NBLK && tid < 16) arr[blockIdx.x * 16 + tid] = 0u;
    f32x4 acc[2] = {};
    const unsigned short* Brow = phiT + (size_t)(n0 + l15) * PIX + kbase + q8;
    const float* X0 = x + (size_t)l15 * PIX + kbase + q8;
    const float* X1 = x + (size_t)(16 + l15) * PIX + kbase + q8;
    #pragma unroll 4
    for (int kk = 0; kk < PIX / 8; kk += 32) {
        bf16x8 bg = ldfrag_g(Brow + kk);
        float4 xa0 = *(const float4*)(X0 + kk), xb0 = *(const float4*)(X0 + kk + 4);
        float4 xa1 = *(const float4*)(X1 + kk), xb1 = *(const float4*)(X1 + kk + 4);
        bf16x8 a0, a1;
        a0[0]=(__bf16)xa0.x; a0[1]=(__bf16)xa0.y; a0[2]=(__bf16)xa0.z; a0[3]=(__bf16)xa0.w;
        a0[4]=(__bf16)xb0.x; a0[5]=(__bf16)xb0.y; a0[6]=(__bf16)xb0.z; a0[7]=(__bf16)xb0.w;
        a1[0]=(__bf16)xa1.x; a1[1]=(__bf16)xa1.y; a1[2]=(__bf16)xa1.z; a1[3]=(__bf16)xa1.w;
        a1[4]=(__bf16)xb1.x; a1[5]=(__bf16)xb1.y; a1[6]=(__bf16)xb1.z; a1[7]=(__bf16)xb1.w;
        acc[0] = __builtin_amdgcn_mfma_f32_16x16x32_bf16(a0, bg, acc[0], 0, 0, 0);
        acc[1] = __builtin_amdgcn_mfma_f32_16x16x32_bf16(a1, bg, acc[1], 0, 0, 0);
    }
    const int q = lane >> 4;
    #pragma unroll
    for (int mt = 0; mt < 2; ++mt)
        #pragma unroll
        for (int r = 0; r < 4; ++r)
            red[w * 512 + (mt * 16 + q * 4 + r) * 16 + l15] = acc[mt][r];
    __syncthreads();
    float s = 0.f;
    #pragma unroll
    for (int w8 = 0; w8 < 8; ++w8) s += red[w8 * 512 + tid];
    const int m = tid >> 4, n = n0 + (tid & 15);
    b[(size_t)m * NEU + n] = s;
}

// ---------------------------------------------------------------------------
// publish this thread's single a-value: gather 4 consecutive lanes' bf16
// pairs into one 8-B agent-scope write-through store.
__device__ __forceinline__ void publish16(unsigned short* slot, size_t idx,
                                          float av, int lane) {
    unsigned int v  = f2b(av);
    unsigned int d0 = v | ((unsigned int)__shfl_xor((int)v, 1, 64) << 16);
    unsigned int hi = (unsigned int)__shfl_xor((int)d0, 2, 64);
    if ((lane & 3) == 0) {
        unsigned long long val = (unsigned long long)d0 | ((unsigned long long)hi << 32);
        __hip_atomic_store((unsigned long long*)slot + (idx >> 2), val,
                           __ATOMIC_RELAXED, __HIP_MEMORY_SCOPE_AGENT);
    }
}

// producer-side epoch bump: all 512 threads' write-through publish stores are
// individually vmcnt(0)-drained at the barrier, so data is at the coherence
// point before the flag store issues.
__device__ __forceinline__ void setflag(unsigned int* arr, unsigned int e,
                                        int tid, int bx) {
    __syncthreads();
    if (tid == 0)
        __hip_atomic_store(arr + bx * 16, e, __ATOMIC_RELAXED, __HIP_MEMORY_SCOPE_AGENT);
}

// ---------------------------------------------------------------------------
// Persistent kernel, 256 blocks x 512 thr -- ALL 256 CUs active.
// Two independent 16-row half-systems x 128 col-groups (32 cols each).
// ROUND-3 STRUCTURE (empirical best of the protocol family: flag 578 <
// wave-drain 638 < sentinel 1278 µs) + two pipeline micro-opts:
//   (1) all 16 A-fragment loads issued upfront (miss stream overlaps MFMA)
//   (2) s_setprio(1) around the MFMA cluster (waves are phase-desynced via
//       per-wave producer polls => scheduler has something to arbitrate)
__global__ void __launch_bounds__(TPB, 2)
lca_persist(const unsigned short* __restrict__ G, const float* __restrict__ b,
            unsigned short* __restrict__ rot, float* __restrict__ aout,
            const float* __restrict__ lamp, unsigned int* __restrict__ arr) {
    __shared__ float red[8 * 512];
    const int tid  = threadIdx.x;
    const int lane = tid & 63, w = tid >> 6;        // 8 waves
    const int l15  = lane & 15, q = lane >> 4;
    const int q8   = q * 8;
    const int c    = blockIdx.x & 127;              // column group (32 cols)
    const int h    = blockIdx.x >> 7;               // batch half (16 rows)
    const int n0   = c * 32;
    const int rb   = h * 16;                        // first batch row
    const int kbase = w * (NEU / 8);                // 512 k per wave
    const int pbase = h * 128 + w * 16;             // first producer flag

    // --- G fragments: 2 n-tiles x 16 k-frags, loaded once, loop-invariant.
    bf16x8 gf[2][16];
    #pragma unroll
    for (int j = 0; j < 2; ++j)
        #pragma unroll
        for (int f = 0; f < 16; ++f)
            gf[j][f] = ldfrag_g(G + (size_t)(n0 + j * 16 + l15) * NEU + kbase + f * 32 + q8);

    // --- per-thread state: ONE output (row = rb + tid>>5, col = n0 + tid&31)
    const int m0i = tid >> 5, nn0 = tid & 31;
    const size_t idx0 = (size_t)(rb + m0i) * NEU + n0 + nn0;
    const float bv0 = b[idx0];
    const float lam = lamp[0];

    // --- step 0 entirely in-register: u1 = ETA*b, a1 = soft(u1) ---
    float uv0 = ETA * bv0;
    float av0 = softt(uv0, lam);

    const size_t aoff0 = (size_t)(rb + l15) * NEU + kbase + q8;  // halves

    publish16(rot, idx0, av0, lane);                 // rot[0]
    setflag(arr, 1u, tid, blockIdx.x);

    for (int step = 1; step < STEPS; ++step) {       // steps 1..98
        const unsigned short* A = rot + (size_t)(step - 1) * SLOT;

        // wait for THIS wave's 16 producers (own half) to publish slot step-1
        {
            const unsigned int* fp = arr + (size_t)(pbase + l15) * 16;
            for (;;) {
                unsigned int v = __hip_atomic_load(fp, __ATOMIC_RELAXED,
                                                   __HIP_MEMORY_SCOPE_AGENT);
                if (__ballot(v < (unsigned int)step) == 0ULL) break;
            }
            // order the A-loads after the poll WITHOUT clobbering all memory:
            // false dependency on the pointer the loads use.
            asm volatile("" : "+s"(A));
        }

        // issue ALL 16 fragment loads upfront: the full L2/L3 miss stream is
        // in flight before the first MFMA waits on fragment 0.
        uint4 rr[16];
        #pragma unroll
        for (int f = 0; f < 16; ++f)
            rr[f] = *(const uint4*)(A + aoff0 + f * 32);

        f32x4 acc00 = {}, acc01 = {};
        __builtin_amdgcn_s_setprio(1);
        #pragma unroll
        for (int f = 0; f < 16; ++f) {
            bf16x8 s = __builtin_bit_cast(bf16x8, rr[f]);
            acc00 = __builtin_amdgcn_mfma_f32_16x16x32_bf16(s, gf[0][f], acc00, 0, 0, 0);
            acc01 = __builtin_amdgcn_mfma_f32_16x16x32_bf16(s, gf[1][f], acc01, 0, 0, 0);
        }
        __builtin_amdgcn_s_setprio(0);

        // stage partials: red[w][ m*32 + nn ],  m = q*4 + r, nn = j*16 + l15
        #pragma unroll
        for (int r = 0; r < 4; ++r) {
            red[w * 512 + (q * 4 + r) * 32 + l15]      = acc00[r];
            red[w * 512 + (q * 4 + r) * 32 + 16 + l15] = acc01[r];
        }
        __syncthreads();
        float s0v = 0.f;
        #pragma unroll
        for (int w8 = 0; w8 < 8; ++w8) s0v += red[w8 * 512 + tid];

        uv0 = fmaf(ETA, bv0 - s0v + av0 - uv0, uv0);
        av0 = softt(uv0, lam);

        if (step == STEPS - 1) {
            aout[idx0] = av0;
        } else {
            publish16(rot + (size_t)step * SLOT, idx0, av0, lane);
            setflag(arr, (unsigned int)(step + 1), tid, blockIdx.x);
        }
    }
}

// ===========================================================================
// Fallback fp32 path (round-1, known correct) for small ws_size
// ===========================================================================
__global__ void lca_init_f(const float* __restrict__ x, const float* __restrict__ phi,
                           float* __restrict__ b, float* __restrict__ u,
                           float* __restrict__ a) {
    const int n  = blockIdx.x * 64 + (threadIdx.x & 63);
    const int bi = blockIdx.y * 4 + (threadIdx.x >> 6);
    const float* xr = x + bi * PIX;
    float acc = 0.f;
    #pragma unroll 4
    for (int p = 0; p < PIX; ++p) acc = fmaf(xr[p], phi[p * NEU + n], acc);
    const int idx = bi * NEU + n;
    b[idx] = acc; u[idx] = 0.f; a[idx] = 0.f;
}
__global__ void lca_s_f(const float* __restrict__ a, const float* __restrict__ phi,
                        float* __restrict__ s) {
    const int lane = threadIdx.x & 63, w = threadIdx.x >> 6;
    const int bi = blockIdx.y, p0 = (blockIdx.x * 4 + w) * 8;
    const float* ar = a + bi * NEU;
    float acc[8] = {};
    for (int i = 0; i < NEU / 64; ++i) {
        const int n = i * 64 + lane;
        const float av = ar[n];
        #pragma unroll
        for (int j = 0; j < 8; ++j) acc[j] = fmaf(av, phi[(p0 + j) * NEU + n], acc[j]);
    }
    float out = 0.f;
    #pragma unroll
    for (int j = 0; j < 8; ++j) {
        float v = acc[j];
        v += __shfl_xor(v, 1, 64); v += __shfl_xor(v, 2, 64); v += __shfl_xor(v, 4, 64);
        v += __shfl_xor(v, 8, 64); v += __shfl_xor(v, 16, 64); v += __shfl_xor(v, 32, 64);
        if (lane == j) out = v;
    }
    if (lane < 8) s[bi * PIX + p0 + lane] = out;
}
__global__ void lca_t_f(const float* __restrict__ s, const float* __restrict__ phi,
                        const float* __restrict__ b, float* __restrict__ u,
                        float* __restrict__ a, const float* __restrict__ lamp) {
    __shared__ float ls[8 * 256];
    const int n = blockIdx.x * 64 + (threadIdx.x & 63);
    const int slot = threadIdx.x >> 6;
    const int bb = blockIdx.y * 8 + slot;
    float acc = 0.f;
    for (int c = 0; c < PIX; c += 256) {
        __syncthreads();
        for (int e = threadIdx.x; e < 8 * 256; e += 512) {
            const int r = e >> 8, p = e & 255;
            ls[e] = s[(blockIdx.y * 8 + r) * PIX + c + p];
        }
        __syncthreads();
        const float* lrow = ls + slot * 256;
        #pragma unroll 8
        for (int p = 0; p < 256; ++p) acc = fmaf(lrow[p], phi[(c + p) * NEU + n], acc);
    }
    const float lam = lamp[0];
    const int idx = bb * NEU + n;
    const float uo = u[idx];
    const float du = b[idx] - acc + a[idx] - uo;
    const float un = fmaf(ETA, du, uo);
    u[idx] = un; a[idx] = softt(un, lam);
}

// ===========================================================================
extern "C" void kernel_launch(void* const* d_in, const int* in_sizes, int n_in,
                              void* d_out, int out_size, void* d_ws, size_t ws_size,
                              hipStream_t stream) {
    const float* x    = (const float*)d_in[0];
    const float* phi  = (const float*)d_in[1];
    const float* lamp = (const float*)d_in[2];
    float* a = (float*)d_out;
    char* ws = (char*)d_ws;

    // rot region (98 x 256 KB) overlays phiT (24 MB): phiT is dead once
    // lca_binit completes, before lca_persist starts.
    const size_t ROT_OFF  = 0;
    const size_t ROT_BYTES= (size_t)(STEPS - 1) * SLOT * 2;         // 25.69 MB
    const size_t PHIT_OFF = 0;                                       // overlay
    const size_t G_OFF    = ROT_OFF + ROT_BYTES;                     // 25.69 MB
    const size_t B_OFF    = G_OFF + (size_t)NEU * NEU * 2;           // +32 MB
    const size_t ARR_OFF  = B_OFF + (size_t)BATCH * NEU * 4;
    const size_t NEED     = ARR_OFF + (size_t)NBLK * 64;             // ~58 MB

    if (ws_size >= NEED) {
        unsigned short* phiT = (unsigned short*)(ws + PHIT_OFF);
        unsigned short* rot  = (unsigned short*)(ws + ROT_OFF);
        unsigned short* G    = (unsigned short*)(ws + G_OFF);
        float*          b    = (float*)(ws + B_OFF);
        unsigned int*   arr  = (unsigned int*)(ws + ARR_OFF);

        transp<<<dim3(NEU / 64, PIX / 64), 256, 0, stream>>>(phi, phiT);
        gemm_G<<<dim3(32, 32), 256, 0, stream>>>(phiT, G);
        lca_binit<<<256, 512, 0, stream>>>(x, phiT, b, arr);

        void* args[6];
        const unsigned short* Gc = G;
        const float* bc = b;
        const float* lc = lamp;
        args[0] = (void*)&Gc;
        args[1] = (void*)&bc;
        args[2] = (void*)&rot;
        args[3] = (void*)&a;
        args[4] = (void*)&lc;
        args[5] = (void*)&arr;
        hipLaunchCooperativeKernel((const void*)lca_persist, dim3(NBLK), dim3(TPB),
                                   args, 0, stream);
    } else {
        float* fws = (float*)d_ws;
        float* b = fws;
        float* u = fws + BATCH * NEU;
        float* s = fws + 2 * BATCH * NEU;
        lca_init_f<<<dim3(64, 8), 256, 0, stream>>>(x, phi, b, u, a);
        for (int it = 0; it < STEPS; ++it) {
            lca_s_f<<<dim3(96, 32), 256, 0, stream>>>(a, phi, s);
            lca_t_f<<<dim3(64, 4), 512, 0, stream>>>(s, phi, b, u, a, lamp);
        }
    }
}